// Round 2
// baseline (270.579 us; speedup 1.0000x reference)
//
#include <hip/hip_runtime.h>
#include <cstdint>
#include <cfloat>

#define BB 2
#define NN 1024
#define KK 512
#define II 16
#define OO 64
#define R2 1.0f

__device__ __forceinline__ float lrelu(float v) { return v > 0.0f ? v : 0.2f * v; }

// ---------------------------------------------------------------------------
// Ball query: one wave per point. Ordered compaction of in-radius indices via
// ballot + prefix popcount. Stores first min(count,K) indices (ushort) and the
// raw in-radius count.
// ---------------------------------------------------------------------------
__global__ __launch_bounds__(256) void ball_query_k(
    const float* __restrict__ pos, unsigned short* __restrict__ idx,
    int* __restrict__ cnt)
{
    const int wave = threadIdx.x >> 6;
    const int lane = threadIdx.x & 63;
    const int p = blockIdx.x * 4 + wave;           // 0 .. B*N-1
    const int b = p >> 10;
    const float cx = pos[p * 3 + 0];
    const float cy = pos[p * 3 + 1];
    const float cz = pos[p * 3 + 2];
    const float* pb = pos + (size_t)b * NN * 3;
    unsigned short* out = idx + (size_t)p * KK;
    int count = 0;
    for (int jb = 0; jb < NN; jb += 64) {
        const int j = jb + lane;
        const float dx = pb[j * 3 + 0] - cx;
        const float dy = pb[j * 3 + 1] - cy;
        const float dz = pb[j * 3 + 2] - cz;
        const float d2 = dx * dx + dy * dy + dz * dz;
        const bool pred = d2 < R2;
        const unsigned long long m = __ballot(pred);
        const int before = __popcll(m & ((1ull << lane) - 1ull));
        const int w = count + before;
        if (pred && w < KK) out[w] = (unsigned short)j;
        count += __popcll(m);
    }
    if (lane == 0) cnt[p] = count;
}

// ---------------------------------------------------------------------------
// Precompute for an SA layer:
//   g[p][c] = b1[c] + pos[p]@W1_xyz[c] + feat[p]@W1_feat[c]
//   t[p][c] = pos[p]@W1_xyz[c]
// One wave per point, lane = channel c.
// ---------------------------------------------------------------------------
template <int C>
__global__ __launch_bounds__(256) void pre_k(
    const float* __restrict__ pos, const float* __restrict__ feat,
    const float* __restrict__ w1, const float* __restrict__ b1,
    float* __restrict__ g, float* __restrict__ t)
{
    const int wave = threadIdx.x >> 6;
    const int c = threadIdx.x & 63;
    const int p = blockIdx.x * 4 + wave;
    const float px = pos[p * 3 + 0];
    const float py = pos[p * 3 + 1];
    const float pz = pos[p * 3 + 2];
    const float s = px * w1[0 * 64 + c] + py * w1[1 * 64 + c] + pz * w1[2 * 64 + c];
    float acc = b1[c] + s;
    const float* f = feat + (size_t)p * C;
#pragma unroll
    for (int q = 0; q < C; ++q)
        acc = fmaf(f[q], w1[(3 + q) * 64 + c], acc);
    g[(size_t)p * 64 + c] = acc;
    t[(size_t)p * 64 + c] = s;
}

// ---------------------------------------------------------------------------
// SA max kernel: one 256-thread block (4 waves) per point. lane = output
// channel; wave handles neighbors k = wave, wave+4, ... Each neighbor:
//   h1 = lrelu(g[j] - t[i])   (lane's own channel)
//   broadcast h1 across lanes via double-buffered LDS (one barrier/iter)
//   h2[c] = lrelu(b2[c] + sum_o h1[o] * w2[o][c]),  running max over k.
// Invalid slots (count < K) contribute exactly 0 to the max.
// ---------------------------------------------------------------------------
__global__ __launch_bounds__(256) void sa_max_k(
    const float* __restrict__ g, const float* __restrict__ t,
    const unsigned short* __restrict__ idx, const int* __restrict__ cnt,
    const float* __restrict__ w2, const float* __restrict__ b2,
    float* __restrict__ out)
{
    const int p = blockIdx.x;                  // point
    const int lane = threadIdx.x & 63;
    const int wave = threadIdx.x >> 6;
    const int b = p >> 10;

    float w2col[64];
#pragma unroll
    for (int o = 0; o < 64; ++o) w2col[o] = w2[o * 64 + lane];
    const float bb = b2[lane];
    const float tc = t[(size_t)p * 64 + lane];

    const int craw = cnt[p];
    const int vc = craw < KK ? craw : KK;
    float lmax = (craw < KK) ? 0.0f : -FLT_MAX;

    const unsigned short* mi = idx + (size_t)p * KK;
    const float* gb = g + (size_t)b * NN * 64;

    __shared__ float h1buf[2][4][64];

    const int iters = (vc + 3) >> 2;
    for (int m = 0; m < iters; ++m) {
        const int k = m * 4 + wave;
        const int buf = m & 1;
        const bool act = k < vc;
        float h1 = 0.0f;
        if (act) {
            const int j = (int)mi[k];
            h1 = lrelu(gb[(size_t)j * 64 + lane] - tc);
        }
        h1buf[buf][wave][lane] = h1;
        __syncthreads();
        if (act) {
            float a0 = bb, a1 = 0.0f, a2 = 0.0f, a3 = 0.0f;
            const float4* h4 = (const float4*)h1buf[buf][wave];
#pragma unroll
            for (int o = 0; o < 16; ++o) {
                const float4 hv = h4[o];
                a0 = fmaf(hv.x, w2col[4 * o + 0], a0);
                a1 = fmaf(hv.y, w2col[4 * o + 1], a1);
                a2 = fmaf(hv.z, w2col[4 * o + 2], a2);
                a3 = fmaf(hv.w, w2col[4 * o + 3], a3);
            }
            const float h2 = lrelu((a0 + a1) + (a2 + a3));
            lmax = fmaxf(lmax, h2);
        }
    }

    __shared__ float red[4][64];
    red[wave][lane] = lmax;
    __syncthreads();
    if (wave == 0) {
        const float mres = fmaxf(fmaxf(red[0][lane], red[1][lane]),
                                 fmaxf(red[2][lane], red[3][lane]));
        out[(size_t)p * 64 + lane] = mres;
    }
}

// ---------------------------------------------------------------------------
// Pointwise epilogue for a layer:
//   xi  = relu(sa @ Wa + ba) @ Wb + bbias
//   out = base @ Wc + bc + xi
// One wave per point, lane = channel. Broadcasts via __shfl.
// ---------------------------------------------------------------------------
template <int CB>
__global__ __launch_bounds__(256) void pw_k(
    const float* __restrict__ sa, const float* __restrict__ base,
    const float* __restrict__ wa, const float* __restrict__ ba,
    const float* __restrict__ wb, const float* __restrict__ bbias,
    const float* __restrict__ wc, const float* __restrict__ bc,
    float* __restrict__ out)
{
    const int wave = threadIdx.x >> 6;
    const int c = threadIdx.x & 63;
    const int p = blockIdx.x * 4 + wave;

    const float sv = sa[(size_t)p * 64 + c];
    float a0 = ba[c], a1 = 0.0f, a2 = 0.0f, a3 = 0.0f;
#pragma unroll
    for (int o = 0; o < 64; o += 4) {
        a0 = fmaf(__shfl(sv, o + 0), wa[(o + 0) * 64 + c], a0);
        a1 = fmaf(__shfl(sv, o + 1), wa[(o + 1) * 64 + c], a1);
        a2 = fmaf(__shfl(sv, o + 2), wa[(o + 2) * 64 + c], a2);
        a3 = fmaf(__shfl(sv, o + 3), wa[(o + 3) * 64 + c], a3);
    }
    const float tmp = fmaxf((a0 + a1) + (a2 + a3), 0.0f);

    float e0 = bbias[c], e1 = 0.0f, e2 = 0.0f, e3 = 0.0f;
#pragma unroll
    for (int o = 0; o < 64; o += 4) {
        e0 = fmaf(__shfl(tmp, o + 0), wb[(o + 0) * 64 + c], e0);
        e1 = fmaf(__shfl(tmp, o + 1), wb[(o + 1) * 64 + c], e1);
        e2 = fmaf(__shfl(tmp, o + 2), wb[(o + 2) * 64 + c], e2);
        e3 = fmaf(__shfl(tmp, o + 3), wb[(o + 3) * 64 + c], e3);
    }
    const float xi = (e0 + e1) + (e2 + e3);

    float r0 = bc[c], r1 = 0.0f, r2 = 0.0f, r3 = 0.0f;
    const float* bp = base + (size_t)p * CB;
#pragma unroll
    for (int f = 0; f < CB; f += 4) {
        r0 = fmaf(bp[f + 0], wc[(f + 0) * 64 + c], r0);
        r1 = fmaf(bp[f + 1], wc[(f + 1) * 64 + c], r1);
        r2 = fmaf(bp[f + 2], wc[(f + 2) * 64 + c], r2);
        r3 = fmaf(bp[f + 3], wc[(f + 3) * 64 + c], r3);
    }
    out[(size_t)p * 64 + c] = ((r0 + r1) + (r2 + r3)) + xi;
}

// ---------------------------------------------------------------------------
extern "C" void kernel_launch(void* const* d_in, const int* in_sizes, int n_in,
                              void* d_out, int out_size, void* d_ws, size_t ws_size,
                              hipStream_t stream)
{
    const float* positions = (const float*)d_in[0];
    const float* features  = (const float*)d_in[1];
    const float* sa0_w1 = (const float*)d_in[2];
    const float* sa0_b1 = (const float*)d_in[3];
    const float* sa0_w2 = (const float*)d_in[4];
    const float* sa0_b2 = (const float*)d_in[5];
    const float* sa1_w1 = (const float*)d_in[6];
    const float* sa1_b1 = (const float*)d_in[7];
    const float* sa1_w2 = (const float*)d_in[8];
    const float* sa1_b2 = (const float*)d_in[9];
    const float* lin0_w1 = (const float*)d_in[10];
    const float* lin0_b1 = (const float*)d_in[11];
    const float* lin0_w2 = (const float*)d_in[12];
    const float* lin0_b2 = (const float*)d_in[13];
    const float* lin1_w1 = (const float*)d_in[14];
    const float* lin1_b1 = (const float*)d_in[15];
    const float* lin1_w2 = (const float*)d_in[16];
    const float* lin1_b2 = (const float*)d_in[17];
    const float* lt0_w = (const float*)d_in[18];
    const float* lt0_b = (const float*)d_in[19];
    const float* lt1_w = (const float*)d_in[20];
    const float* lt1_b = (const float*)d_in[21];

    const int P = BB * NN;   // 2048 points

    // workspace layout
    unsigned short* idx = (unsigned short*)d_ws;               // P*K ushort  (2 MiB)
    int* cnt = (int*)(idx + (size_t)P * KK);                   // P ints
    float* g  = (float*)(cnt + P);                             // P*64
    float* t  = g  + (size_t)P * OO;                           // P*64
    float* sa = t  + (size_t)P * OO;                           // P*64
    float* x  = sa + (size_t)P * OO;                           // P*64

    float* out = (float*)d_out;

    // 1. ball query (shared by both layers)
    ball_query_k<<<P / 4, 256, 0, stream>>>(positions, idx, cnt);

    // 2. layer 0
    pre_k<II><<<P / 4, 256, 0, stream>>>(positions, features, sa0_w1, sa0_b1, g, t);
    sa_max_k<<<P, 256, 0, stream>>>(g, t, idx, cnt, sa0_w2, sa0_b2, sa);
    pw_k<II><<<P / 4, 256, 0, stream>>>(sa, features, lin0_w1, lin0_b1,
                                        lin0_w2, lin0_b2, lt0_w, lt0_b, x);

    // 3. layer 1
    pre_k<OO><<<P / 4, 256, 0, stream>>>(positions, x, sa1_w1, sa1_b1, g, t);
    sa_max_k<<<P, 256, 0, stream>>>(g, t, idx, cnt, sa1_w2, sa1_b2, sa);
    pw_k<OO><<<P / 4, 256, 0, stream>>>(sa, x, lin1_w1, lin1_b1,
                                        lin1_w2, lin1_b2, lt1_w, lt1_b, out);
}

// Round 4
// 215.068 us; speedup vs baseline: 1.2581x; 1.2581x over previous
//
#include <hip/hip_runtime.h>
#include <cstdint>
#include <cfloat>

#define BB 2
#define NN 1024
#define KK 512
#define II 16
#define OO 64
#define R2 1.0f
#define PTOT (BB * NN)

__device__ __forceinline__ float lrelu(float v) { return v > 0.0f ? v : 0.2f * v; }

// ---------------------------------------------------------------------------
// setup_k: blocks [0, P/4)       -> ball query (one wave per point)
//          blocks [P/4, P/2)     -> layer-0 precompute g0/t0 (one wave per point)
//   g[p][c] = b1[c] + pos[p]@W1_xyz[c] + feat[p]@W1_feat[c]
//   t[p][c] = pos[p]@W1_xyz[c]
// ---------------------------------------------------------------------------
__global__ __launch_bounds__(256) void setup_k(
    const float* __restrict__ pos, const float* __restrict__ feat,
    const float* __restrict__ w1, const float* __restrict__ b1,
    unsigned short* __restrict__ idx, int* __restrict__ cnt,
    float* __restrict__ g, float* __restrict__ t)
{
    const int wave = threadIdx.x >> 6;
    const int lane = threadIdx.x & 63;

    if (blockIdx.x < PTOT / 4) {
        // ---- ball query: ordered compaction via ballot + prefix popcount ----
        const int p = blockIdx.x * 4 + wave;
        const int b = p >> 10;
        const float cx = pos[p * 3 + 0];
        const float cy = pos[p * 3 + 1];
        const float cz = pos[p * 3 + 2];
        const float* pb = pos + (size_t)b * NN * 3;
        unsigned short* op = idx + (size_t)p * KK;
        int count = 0;
        for (int jb = 0; jb < NN; jb += 64) {
            const int j = jb + lane;
            const float dx = pb[j * 3 + 0] - cx;
            const float dy = pb[j * 3 + 1] - cy;
            const float dz = pb[j * 3 + 2] - cz;
            const float d2 = dx * dx + dy * dy + dz * dz;
            const bool pred = d2 < R2;
            const unsigned long long m = __ballot(pred);
            const int before = __popcll(m & ((1ull << lane) - 1ull));
            const int w = count + before;
            if (pred && w < KK) op[w] = (unsigned short)j;
            count += __popcll(m);
        }
        if (lane == 0) cnt[p] = count;
    } else {
        // ---- layer-0 precompute (C = II = 16) ----
        const int p = (blockIdx.x - PTOT / 4) * 4 + wave;
        const int c = lane;
        const float px = pos[p * 3 + 0];
        const float py = pos[p * 3 + 1];
        const float pz = pos[p * 3 + 2];
        const float s = px * w1[0 * 64 + c] + py * w1[1 * 64 + c] + pz * w1[2 * 64 + c];
        float acc = b1[c] + s;
        const float* f = feat + (size_t)p * II;
#pragma unroll
        for (int q = 0; q < II; ++q)
            acc = fmaf(f[q], w1[(3 + q) * 64 + c], acc);
        g[(size_t)p * 64 + c] = acc;
        t[(size_t)p * 64 + c] = s;
    }
}

// ---------------------------------------------------------------------------
// sa_fused_k<CB, LAST>: one 256-thread block (4 waves) per point.
// Phase 1 (no barriers): wave w processes neighbors k = w, w+4, ...
//   h1 = lrelu(g[j][lane] - t[p][lane]); self-broadcast via own LDS row
//   (same-wave RAW -> lgkmcnt only, no __syncthreads);
//   h2[c] = lrelu(b2[c] + sum_o h1[o]*w2[o][c]); running per-lane max.
//   Next neighbor's g-row is software-prefetched.
// Phase 2 (one barrier): cross-wave max in wave 0, then fused epilogue:
//   xi = relu(sa@wa+ba)@wb+bbias;  x = base@wc+bc + xi  -> xout
//   if !LAST: next layer's precompute g1/t1 from x (all in registers).
// Invalid slots (cnt < K) contribute exactly 0 to the max (lmax init 0).
// ---------------------------------------------------------------------------
template <int CB, bool LAST>
__global__ __launch_bounds__(256) void sa_fused_k(
    const float* __restrict__ g, const float* __restrict__ t,
    const unsigned short* __restrict__ idx, const int* __restrict__ cnt,
    const float* __restrict__ w2, const float* __restrict__ b2,
    const float* __restrict__ wa, const float* __restrict__ ba,
    const float* __restrict__ wb, const float* __restrict__ bbias,
    const float* __restrict__ wc, const float* __restrict__ bc,
    const float* __restrict__ base, const float* __restrict__ pos,
    const float* __restrict__ w1n, const float* __restrict__ b1n,
    float* __restrict__ xout, float* __restrict__ gn, float* __restrict__ tn)
{
    const int p = blockIdx.x;
    const int lane = threadIdx.x & 63;
    const int wave = threadIdx.x >> 6;
    const int b = p >> 10;

    float w2col[64];
#pragma unroll
    for (int o = 0; o < 64; ++o) w2col[o] = w2[o * 64 + lane];
    const float bb2 = b2[lane];
    const float tc = t[(size_t)p * 64 + lane];

    const int craw = cnt[p];
    const int vc = craw < KK ? craw : KK;
    float lmax = (craw < KK) ? 0.0f : -FLT_MAX;

    const unsigned short* mi = idx + (size_t)p * KK;
    const float* gb = g + (size_t)b * NN * 64;

    __shared__ float buf[4][64];

    // barrier-free neighbor loop, stride 4, prefetched
    int k = wave;
    float hrow = 0.0f;
    if (k < vc) hrow = gb[(size_t)mi[k] * 64 + lane];
    while (k < vc) {
        const int k2 = k + 4;
        float hrow2 = 0.0f;
        if (k2 < vc) hrow2 = gb[(size_t)mi[k2] * 64 + lane];

        const float h1 = lrelu(hrow - tc);
        buf[wave][lane] = h1;                       // own row: no barrier needed
        float a0 = bb2, a1 = 0.0f, a2 = 0.0f, a3 = 0.0f;
        const float4* h4 = (const float4*)buf[wave];
#pragma unroll
        for (int o = 0; o < 16; ++o) {
            const float4 hv = h4[o];
            a0 = fmaf(hv.x, w2col[4 * o + 0], a0);
            a1 = fmaf(hv.y, w2col[4 * o + 1], a1);
            a2 = fmaf(hv.z, w2col[4 * o + 2], a2);
            a3 = fmaf(hv.w, w2col[4 * o + 3], a3);
        }
        lmax = fmaxf(lmax, lrelu((a0 + a1) + (a2 + a3)));

        hrow = hrow2;
        k = k2;
    }

    buf[wave][lane] = lmax;                          // reuse LDS for reduction
    __syncthreads();
    if (wave == 0) {
        const float m = fmaxf(fmaxf(buf[0][lane], buf[1][lane]),
                              fmaxf(buf[2][lane], buf[3][lane]));

        // pw: tmp = relu(m@wa + ba)
        float a0 = ba[lane], a1 = 0.0f, a2 = 0.0f, a3 = 0.0f;
#pragma unroll
        for (int o = 0; o < 64; o += 4) {
            a0 = fmaf(__shfl(m, o + 0), wa[(o + 0) * 64 + lane], a0);
            a1 = fmaf(__shfl(m, o + 1), wa[(o + 1) * 64 + lane], a1);
            a2 = fmaf(__shfl(m, o + 2), wa[(o + 2) * 64 + lane], a2);
            a3 = fmaf(__shfl(m, o + 3), wa[(o + 3) * 64 + lane], a3);
        }
        const float tmp = fmaxf((a0 + a1) + (a2 + a3), 0.0f);

        // xi = tmp@wb + bbias
        float e0 = bbias[lane], e1 = 0.0f, e2 = 0.0f, e3 = 0.0f;
#pragma unroll
        for (int o = 0; o < 64; o += 4) {
            e0 = fmaf(__shfl(tmp, o + 0), wb[(o + 0) * 64 + lane], e0);
            e1 = fmaf(__shfl(tmp, o + 1), wb[(o + 1) * 64 + lane], e1);
            e2 = fmaf(__shfl(tmp, o + 2), wb[(o + 2) * 64 + lane], e2);
            e3 = fmaf(__shfl(tmp, o + 3), wb[(o + 3) * 64 + lane], e3);
        }
        const float xi = (e0 + e1) + (e2 + e3);

        // residual: base@wc + bc   (base row is wave-uniform -> scalar loads)
        float r0 = bc[lane], r1 = 0.0f, r2 = 0.0f, r3 = 0.0f;
        const float* bp = base + (size_t)p * CB;
#pragma unroll
        for (int f = 0; f < CB; f += 4) {
            r0 = fmaf(bp[f + 0], wc[(f + 0) * 64 + lane], r0);
            r1 = fmaf(bp[f + 1], wc[(f + 1) * 64 + lane], r1);
            r2 = fmaf(bp[f + 2], wc[(f + 2) * 64 + lane], r2);
            r3 = fmaf(bp[f + 3], wc[(f + 3) * 64 + lane], r3);
        }
        const float xv = ((r0 + r1) + (r2 + r3)) + xi;
        xout[(size_t)p * 64 + lane] = xv;

        if constexpr (!LAST) {
            // next layer's precompute: t1 = pos@W1_xyz; g1 = b1 + t1 + x@W1_feat
            const float px = pos[p * 3 + 0];
            const float py = pos[p * 3 + 1];
            const float pz = pos[p * 3 + 2];
            const float s = px * w1n[0 * 64 + lane] + py * w1n[1 * 64 + lane]
                          + pz * w1n[2 * 64 + lane];
            float g0 = b1n[lane] + s, g1v = 0.0f, g2 = 0.0f, g3 = 0.0f;
#pragma unroll
            for (int q = 0; q < 64; q += 4) {
                g0  = fmaf(__shfl(xv, q + 0), w1n[(3 + q + 0) * 64 + lane], g0);
                g1v = fmaf(__shfl(xv, q + 1), w1n[(3 + q + 1) * 64 + lane], g1v);
                g2  = fmaf(__shfl(xv, q + 2), w1n[(3 + q + 2) * 64 + lane], g2);
                g3  = fmaf(__shfl(xv, q + 3), w1n[(3 + q + 3) * 64 + lane], g3);
            }
            gn[(size_t)p * 64 + lane] = (g0 + g1v) + (g2 + g3);
            tn[(size_t)p * 64 + lane] = s;
        }
    }
}

// ---------------------------------------------------------------------------
extern "C" void kernel_launch(void* const* d_in, const int* in_sizes, int n_in,
                              void* d_out, int out_size, void* d_ws, size_t ws_size,
                              hipStream_t stream)
{
    const float* positions = (const float*)d_in[0];
    const float* features  = (const float*)d_in[1];
    const float* sa0_w1 = (const float*)d_in[2];
    const float* sa0_b1 = (const float*)d_in[3];
    const float* sa0_w2 = (const float*)d_in[4];
    const float* sa0_b2 = (const float*)d_in[5];
    const float* sa1_w1 = (const float*)d_in[6];
    const float* sa1_b1 = (const float*)d_in[7];
    const float* sa1_w2 = (const float*)d_in[8];
    const float* sa1_b2 = (const float*)d_in[9];
    const float* lin0_w1 = (const float*)d_in[10];
    const float* lin0_b1 = (const float*)d_in[11];
    const float* lin0_w2 = (const float*)d_in[12];
    const float* lin0_b2 = (const float*)d_in[13];
    const float* lin1_w1 = (const float*)d_in[14];
    const float* lin1_b1 = (const float*)d_in[15];
    const float* lin1_w2 = (const float*)d_in[16];
    const float* lin1_b2 = (const float*)d_in[17];
    const float* lt0_w = (const float*)d_in[18];
    const float* lt0_b = (const float*)d_in[19];
    const float* lt1_w = (const float*)d_in[20];
    const float* lt1_b = (const float*)d_in[21];

    const int P = PTOT;   // 2048 points

    // workspace layout
    unsigned short* idx = (unsigned short*)d_ws;               // P*K ushort (2 MiB)
    int* cnt = (int*)(idx + (size_t)P * KK);                   // P ints
    float* g0 = (float*)(cnt + P);                             // P*64
    float* t0 = g0 + (size_t)P * OO;                           // P*64
    float* g1 = t0 + (size_t)P * OO;                           // P*64
    float* t1 = g1 + (size_t)P * OO;                           // P*64
    float* x  = t1 + (size_t)P * OO;                           // P*64

    float* out = (float*)d_out;

    // 1. ball query + layer-0 precompute (one dispatch)
    setup_k<<<P / 2, 256, 0, stream>>>(positions, features, sa0_w1, sa0_b1,
                                       idx, cnt, g0, t0);

    // 2. layer 0: SA-max + pointwise + lt residual + layer-1 precompute
    sa_fused_k<II, false><<<P, 256, 0, stream>>>(
        g0, t0, idx, cnt, sa0_w2, sa0_b2,
        lin0_w1, lin0_b1, lin0_w2, lin0_b2, lt0_w, lt0_b,
        features, positions, sa1_w1, sa1_b1, x, g1, t1);

    // 3. layer 1: SA-max + pointwise + lt residual -> output
    sa_fused_k<OO, true><<<P, 256, 0, stream>>>(
        g1, t1, idx, cnt, sa1_w2, sa1_b2,
        lin1_w1, lin1_b1, lin1_w2, lin1_b2, lt1_w, lt1_b,
        x, positions, nullptr, nullptr, out, nullptr, nullptr);
}

// Round 9
// 170.374 us; speedup vs baseline: 1.5882x; 1.2623x over previous
//
#include <hip/hip_runtime.h>
#include <cstdint>
#include <cfloat>

#define BB 2
#define NN 1024
#define KK 512
#define II 16
#define OO 64
#define R2 1.0f
#define PTOT (BB * NN)

typedef __attribute__((ext_vector_type(8))) short short8;   // 8 bf16 = 4 VGPR
typedef __attribute__((ext_vector_type(4))) float f32x4;

__device__ __forceinline__ float lrelu(float v) { return v > 0.0f ? v : 0.2f * v; }

// bf16 RNE via bit ops (no header-API dependence); split lo = exact fp32 residual
__device__ __forceinline__ unsigned short f2bf(float f) {
    unsigned int x = __float_as_uint(f);
    return (unsigned short)((x + 0x7fffu + ((x >> 16) & 1u)) >> 16);
}
__device__ __forceinline__ float bf2f(unsigned short h) {
    return __uint_as_float(((unsigned int)h) << 16);
}

// ---------------------------------------------------------------------------
// setup_k: blocks [0, P/4)   -> ball query (one wave per point)
//          blocks [P/4, P/2) -> layer-0 precompute g0/t0
// ---------------------------------------------------------------------------
__global__ __launch_bounds__(256) void setup_k(
    const float* __restrict__ pos, const float* __restrict__ feat,
    const float* __restrict__ w1, const float* __restrict__ b1,
    unsigned short* __restrict__ idx, int* __restrict__ cnt,
    float* __restrict__ g, float* __restrict__ t)
{
    const int wave = threadIdx.x >> 6;
    const int lane = threadIdx.x & 63;

    if (blockIdx.x < PTOT / 4) {
        const int p = blockIdx.x * 4 + wave;
        const int b = p >> 10;
        const float cx = pos[p * 3 + 0];
        const float cy = pos[p * 3 + 1];
        const float cz = pos[p * 3 + 2];
        const float* pb = pos + (size_t)b * NN * 3;
        unsigned short* op = idx + (size_t)p * KK;
        int count = 0;
        for (int jb = 0; jb < NN; jb += 64) {
            const int j = jb + lane;
            const float dx = pb[j * 3 + 0] - cx;
            const float dy = pb[j * 3 + 1] - cy;
            const float dz = pb[j * 3 + 2] - cz;
            const float d2 = dx * dx + dy * dy + dz * dz;
            const bool pred = d2 < R2;
            const unsigned long long m = __ballot(pred);
            const int before = __popcll(m & ((1ull << lane) - 1ull));
            const int w = count + before;
            if (pred && w < KK) op[w] = (unsigned short)j;
            count += __popcll(m);
        }
        if (lane == 0) cnt[p] = count;
    } else {
        const int p = (blockIdx.x - PTOT / 4) * 4 + wave;
        const int c = lane;
        const float px = pos[p * 3 + 0];
        const float py = pos[p * 3 + 1];
        const float pz = pos[p * 3 + 2];
        const float s = px * w1[0 * 64 + c] + py * w1[1 * 64 + c] + pz * w1[2 * 64 + c];
        float acc = b1[c] + s;
        const float* f = feat + (size_t)p * II;
#pragma unroll
        for (int q = 0; q < II; ++q)
            acc = fmaf(f[q], w1[(3 + q) * 64 + c], acc);
        g[(size_t)p * 64 + c] = acc;
        t[(size_t)p * 64 + c] = s;
    }
}

// ---------------------------------------------------------------------------
// sa_fused_k<CB, LAST>: one 256-thread block (4 waves) per point.
// Wave w handles neighbor tiles t = w, w+4, ... of 16 neighbors each.
// Per tile: per-lane gather of h1 fragment straight from g (A row = lane&15,
// k-slice = (lane>>4)*8+j), split into bf16 hi/lo; 3 MFMAs per (kfrag,ct)
// give ~fp32-accurate H1@W2; bias+lrelu+mask folded into a running max.
// D layout (m89-verified): col = lane&15 (channel), row = (lane>>4)*4+reg
// (neighbor). Pad rows contribute 0; final max(m,0) iff cnt<K matches the
// reference's mask-then-max semantics exactly.
// One barrier total; wave 0 runs the fused pointwise epilogue (+ next layer's
// precompute when !LAST).
// ---------------------------------------------------------------------------
template <int CB, bool LAST>
__global__ __launch_bounds__(256) void sa_fused_k(
    const float* __restrict__ g, const float* __restrict__ t,
    const unsigned short* __restrict__ idx, const int* __restrict__ cnt,
    const float* __restrict__ w2, const float* __restrict__ b2,
    const float* __restrict__ wa, const float* __restrict__ ba,
    const float* __restrict__ wb, const float* __restrict__ bbias,
    const float* __restrict__ wc, const float* __restrict__ bc,
    const float* __restrict__ base, const float* __restrict__ pos,
    const float* __restrict__ w1n, const float* __restrict__ b1n,
    float* __restrict__ xout, float* __restrict__ gn, float* __restrict__ tn)
{
    const int p = blockIdx.x;
    const int lane = threadIdx.x & 63;
    const int wave = threadIdx.x >> 6;
    const int b = p >> 10;
    const int row = lane & 15;   // A-row / D-col position
    const int kg  = lane >> 4;   // k-group (8 consecutive k per group)

    // ---- B fragments of W2 (bf16 hi/lo), loaded once. col = row (lane&15) ----
    short8 bh[2][4], bl[2][4];
#pragma unroll
    for (int kf = 0; kf < 2; ++kf)
#pragma unroll
        for (int ct = 0; ct < 4; ++ct)
#pragma unroll
            for (int j = 0; j < 8; ++j) {
                const float w = w2[(kf * 32 + kg * 8 + j) * 64 + ct * 16 + row];
                const unsigned short h = f2bf(w);
                bh[kf][ct][j] = (short)h;
                bl[kf][ct][j] = (short)f2bf(w - bf2f(h));
            }

    float b2v[4];
#pragma unroll
    for (int ct = 0; ct < 4; ++ct) b2v[ct] = b2[ct * 16 + row];

    // t fragment: channels kg*8+j (kfrag0) and 32+kg*8+j (kfrag1)
    const float* tp = t + (size_t)p * 64;
    float tv0[8], tv1[8];
#pragma unroll
    for (int j = 0; j < 8; ++j) { tv0[j] = tp[kg * 8 + j]; tv1[j] = tp[32 + kg * 8 + j]; }

    const int craw = cnt[p];
    const int vc = craw < KK ? craw : KK;
    const unsigned short* mi = idx + (size_t)p * KK;
    const float* gbp = g + (size_t)b * NN * 64;

    float lmaxv[4] = {-FLT_MAX, -FLT_MAX, -FLT_MAX, -FLT_MAX};
    const int ntiles = (vc + 15) >> 4;

    for (int tile = wave; tile < ntiles; tile += 4) {
        const int j16 = tile * 16 + row;
        const int jc = j16 < vc ? j16 : vc - 1;          // clamp: masked later
        const int jidx = (int)mi[jc];
        const float* grow = gbp + (size_t)jidx * 64 + kg * 8;
        const float4 ga = *(const float4*)grow;
        const float4 gb2 = *(const float4*)(grow + 4);
        const float4 gc = *(const float4*)(grow + 32);
        const float4 gd = *(const float4*)(grow + 36);
        const float v0[8] = {ga.x, ga.y, ga.z, ga.w, gb2.x, gb2.y, gb2.z, gb2.w};
        const float v1[8] = {gc.x, gc.y, gc.z, gc.w, gd.x, gd.y, gd.z, gd.w};

        short8 ah0, al0, ah1, al1;
#pragma unroll
        for (int j = 0; j < 8; ++j) {
            const float h1a = lrelu(v0[j] - tv0[j]);
            const unsigned short ha = f2bf(h1a);
            ah0[j] = (short)ha;
            al0[j] = (short)f2bf(h1a - bf2f(ha));
            const float h1b = lrelu(v1[j] - tv1[j]);
            const unsigned short hb = f2bf(h1b);
            ah1[j] = (short)hb;
            al1[j] = (short)f2bf(h1b - bf2f(hb));
        }

#pragma unroll
        for (int ct = 0; ct < 4; ++ct) {
            f32x4 a = {0.0f, 0.0f, 0.0f, 0.0f};
            a = __builtin_amdgcn_mfma_f32_16x16x32_bf16(ah0, bh[0][ct], a, 0, 0, 0);
            a = __builtin_amdgcn_mfma_f32_16x16x32_bf16(al0, bh[0][ct], a, 0, 0, 0);
            a = __builtin_amdgcn_mfma_f32_16x16x32_bf16(ah0, bl[0][ct], a, 0, 0, 0);
            a = __builtin_amdgcn_mfma_f32_16x16x32_bf16(ah1, bh[1][ct], a, 0, 0, 0);
            a = __builtin_amdgcn_mfma_f32_16x16x32_bf16(al1, bh[1][ct], a, 0, 0, 0);
            a = __builtin_amdgcn_mfma_f32_16x16x32_bf16(ah1, bl[1][ct], a, 0, 0, 0);
#pragma unroll
            for (int r = 0; r < 4; ++r) {
                const int nb = tile * 16 + kg * 4 + r;   // D row = neighbor
                const float h2 = lrelu(a[r] + b2v[ct]);
                lmaxv[ct] = fmaxf(lmaxv[ct], nb < vc ? h2 : 0.0f);
            }
        }
    }

    // cross-lane (row-group) then cross-wave max
    __shared__ float red[4][64];
#pragma unroll
    for (int ct = 0; ct < 4; ++ct) {
        lmaxv[ct] = fmaxf(lmaxv[ct], __shfl_xor(lmaxv[ct], 16));
        lmaxv[ct] = fmaxf(lmaxv[ct], __shfl_xor(lmaxv[ct], 32));
    }
    if (lane < 16) {
#pragma unroll
        for (int ct = 0; ct < 4; ++ct) red[wave][ct * 16 + lane] = lmaxv[ct];
    }
    __syncthreads();

    if (wave == 0) {
        float m = fmaxf(fmaxf(red[0][lane], red[1][lane]),
                        fmaxf(red[2][lane], red[3][lane]));
        if (craw < KK) m = fmaxf(m, 0.0f);   // reference: zero slots in the max

        // pw: tmp = relu(m@wa + ba)
        float a0 = ba[lane], a1 = 0.0f, a2 = 0.0f, a3 = 0.0f;
#pragma unroll
        for (int o = 0; o < 64; o += 4) {
            a0 = fmaf(__shfl(m, o + 0), wa[(o + 0) * 64 + lane], a0);
            a1 = fmaf(__shfl(m, o + 1), wa[(o + 1) * 64 + lane], a1);
            a2 = fmaf(__shfl(m, o + 2), wa[(o + 2) * 64 + lane], a2);
            a3 = fmaf(__shfl(m, o + 3), wa[(o + 3) * 64 + lane], a3);
        }
        const float tmp = fmaxf((a0 + a1) + (a2 + a3), 0.0f);

        // xi = tmp@wb + bbias
        float e0 = bbias[lane], e1 = 0.0f, e2 = 0.0f, e3 = 0.0f;
#pragma unroll
        for (int o = 0; o < 64; o += 4) {
            e0 = fmaf(__shfl(tmp, o + 0), wb[(o + 0) * 64 + lane], e0);
            e1 = fmaf(__shfl(tmp, o + 1), wb[(o + 1) * 64 + lane], e1);
            e2 = fmaf(__shfl(tmp, o + 2), wb[(o + 2) * 64 + lane], e2);
            e3 = fmaf(__shfl(tmp, o + 3), wb[(o + 3) * 64 + lane], e3);
        }
        const float xi = (e0 + e1) + (e2 + e3);

        // residual: base@wc + bc
        float r0 = bc[lane], r1 = 0.0f, r2 = 0.0f, r3 = 0.0f;
        const float* bp = base + (size_t)p * CB;
#pragma unroll
        for (int f = 0; f < CB; f += 4) {
            r0 = fmaf(bp[f + 0], wc[(f + 0) * 64 + lane], r0);
            r1 = fmaf(bp[f + 1], wc[(f + 1) * 64 + lane], r1);
            r2 = fmaf(bp[f + 2], wc[(f + 2) * 64 + lane], r2);
            r3 = fmaf(bp[f + 3], wc[(f + 3) * 64 + lane], r3);
        }
        const float xv = ((r0 + r1) + (r2 + r3)) + xi;
        xout[(size_t)p * 64 + lane] = xv;

        if constexpr (!LAST) {
            const float px = pos[p * 3 + 0];
            const float py = pos[p * 3 + 1];
            const float pz = pos[p * 3 + 2];
            const float s = px * w1n[0 * 64 + lane] + py * w1n[1 * 64 + lane]
                          + pz * w1n[2 * 64 + lane];
            float g0 = b1n[lane] + s, g1v = 0.0f, g2 = 0.0f, g3 = 0.0f;
#pragma unroll
            for (int q = 0; q < 64; q += 4) {
                g0  = fmaf(__shfl(xv, q + 0), w1n[(3 + q + 0) * 64 + lane], g0);
                g1v = fmaf(__shfl(xv, q + 1), w1n[(3 + q + 1) * 64 + lane], g1v);
                g2  = fmaf(__shfl(xv, q + 2), w1n[(3 + q + 2) * 64 + lane], g2);
                g3  = fmaf(__shfl(xv, q + 3), w1n[(3 + q + 3) * 64 + lane], g3);
            }
            gn[(size_t)p * 64 + lane] = (g0 + g1v) + (g2 + g3);
            tn[(size_t)p * 64 + lane] = s;
        }
    }
}

// ---------------------------------------------------------------------------
extern "C" void kernel_launch(void* const* d_in, const int* in_sizes, int n_in,
                              void* d_out, int out_size, void* d_ws, size_t ws_size,
                              hipStream_t stream)
{
    const float* positions = (const float*)d_in[0];
    const float* features  = (const float*)d_in[1];
    const float* sa0_w1 = (const float*)d_in[2];
    const float* sa0_b1 = (const float*)d_in[3];
    const float* sa0_w2 = (const float*)d_in[4];
    const float* sa0_b2 = (const float*)d_in[5];
    const float* sa1_w1 = (const float*)d_in[6];
    const float* sa1_b1 = (const float*)d_in[7];
    const float* sa1_w2 = (const float*)d_in[8];
    const float* sa1_b2 = (const float*)d_in[9];
    const float* lin0_w1 = (const float*)d_in[10];
    const float* lin0_b1 = (const float*)d_in[11];
    const float* lin0_w2 = (const float*)d_in[12];
    const float* lin0_b2 = (const float*)d_in[13];
    const float* lin1_w1 = (const float*)d_in[14];
    const float* lin1_b1 = (const float*)d_in[15];
    const float* lin1_w2 = (const float*)d_in[16];
    const float* lin1_b2 = (const float*)d_in[17];
    const float* lt0_w = (const float*)d_in[18];
    const float* lt0_b = (const float*)d_in[19];
    const float* lt1_w = (const float*)d_in[20];
    const float* lt1_b = (const float*)d_in[21];

    const int P = PTOT;   // 2048 points

    unsigned short* idx = (unsigned short*)d_ws;               // P*K ushort (2 MiB)
    int* cnt = (int*)(idx + (size_t)P * KK);                   // P ints
    float* g0 = (float*)(cnt + P);                             // P*64
    float* t0 = g0 + (size_t)P * OO;
    float* g1 = t0 + (size_t)P * OO;
    float* t1 = g1 + (size_t)P * OO;
    float* x  = t1 + (size_t)P * OO;

    float* out = (float*)d_out;

    setup_k<<<P / 2, 256, 0, stream>>>(positions, features, sa0_w1, sa0_b1,
                                       idx, cnt, g0, t0);

    sa_fused_k<II, false><<<P, 256, 0, stream>>>(
        g0, t0, idx, cnt, sa0_w2, sa0_b2,
        lin0_w1, lin0_b1, lin0_w2, lin0_b2, lt0_w, lt0_b,
        features, positions, sa1_w1, sa1_b1, x, g1, t1);

    sa_fused_k<OO, true><<<P, 256, 0, stream>>>(
        g1, t1, idx, cnt, sa1_w2, sa1_b2,
        lin1_w1, lin1_b1, lin1_w2, lin1_b2, lt1_w, lt1_b,
        x, positions, nullptr, nullptr, out, nullptr, nullptr);
}

// Round 10
// 159.076 us; speedup vs baseline: 1.7009x; 1.0710x over previous
//
#include <hip/hip_runtime.h>
#include <cstdint>
#include <cfloat>

#define BB 2
#define NN 1024
#define KK 512
#define II 16
#define OO 64
#define R2 1.0f
#define PTOT (BB * NN)

typedef __attribute__((ext_vector_type(8))) short short8;   // 8 bf16 = 4 VGPR
typedef __attribute__((ext_vector_type(4))) float f32x4;

__device__ __forceinline__ float lrelu(float v) { return v > 0.0f ? v : 0.2f * v; }

// bf16 RNE via bit ops; split lo = bf16(fp32 residual)
__device__ __forceinline__ unsigned short f2bf(float f) {
    unsigned int x = __float_as_uint(f);
    return (unsigned short)((x + 0x7fffu + ((x >> 16) & 1u)) >> 16);
}
__device__ __forceinline__ float bf2f(unsigned short h) {
    return __uint_as_float(((unsigned int)h) << 16);
}

// ---------------------------------------------------------------------------
// setup_k: blocks [0, P/4)       -> ball query (one wave per point)
//          blocks [P/4, P/2)     -> layer-0 precompute g0/t0
//          blocks P/2, P/2+1     -> W2 bf16 hi/lo pre-split, fragment order
//                                   dst[((kf*4+ct)*64+lane)*8+j] =
//                                     split(w2[(kf*32+(lane>>4)*8+j)*64+ct*16+(lane&15)])
// ---------------------------------------------------------------------------
__global__ __launch_bounds__(256) void setup_k(
    const float* __restrict__ pos, const float* __restrict__ feat,
    const float* __restrict__ w1, const float* __restrict__ b1,
    const float* __restrict__ w2l0, const float* __restrict__ w2l1,
    unsigned short* __restrict__ idx, int* __restrict__ cnt,
    float* __restrict__ g, float* __restrict__ t,
    unsigned short* __restrict__ bh0, unsigned short* __restrict__ bl0,
    unsigned short* __restrict__ bh1, unsigned short* __restrict__ bl1)
{
    const int wave = threadIdx.x >> 6;
    const int lane = threadIdx.x & 63;

    if (blockIdx.x < PTOT / 4) {
        // ---- ball query: ordered compaction via ballot + prefix popcount ----
        const int p = blockIdx.x * 4 + wave;
        const int b = p >> 10;
        const float cx = pos[p * 3 + 0];
        const float cy = pos[p * 3 + 1];
        const float cz = pos[p * 3 + 2];
        const float* pb = pos + (size_t)b * NN * 3;
        unsigned short* op = idx + (size_t)p * KK;
        int count = 0;
        for (int jb = 0; jb < NN; jb += 64) {
            const int j = jb + lane;
            const float dx = pb[j * 3 + 0] - cx;
            const float dy = pb[j * 3 + 1] - cy;
            const float dz = pb[j * 3 + 2] - cz;
            const float d2 = dx * dx + dy * dy + dz * dz;
            const bool pred = d2 < R2;
            const unsigned long long m = __ballot(pred);
            const int before = __popcll(m & ((1ull << lane) - 1ull));
            const int w = count + before;
            if (pred && w < KK) op[w] = (unsigned short)j;
            count += __popcll(m);
        }
        if (lane == 0) cnt[p] = count;
    } else if (blockIdx.x < PTOT / 2) {
        // ---- layer-0 precompute (C = II = 16) ----
        const int p = (blockIdx.x - PTOT / 4) * 4 + wave;
        const int c = lane;
        const float px = pos[p * 3 + 0];
        const float py = pos[p * 3 + 1];
        const float pz = pos[p * 3 + 2];
        const float s = px * w1[0 * 64 + c] + py * w1[1 * 64 + c] + pz * w1[2 * 64 + c];
        float acc = b1[c] + s;
        const float* f = feat + (size_t)p * II;
#pragma unroll
        for (int q = 0; q < II; ++q)
            acc = fmaf(f[q], w1[(3 + q) * 64 + c], acc);
        g[(size_t)p * 64 + c] = acc;
        t[(size_t)p * 64 + c] = s;
    } else {
        // ---- W2 fragment pre-split: one block per layer ----
        const int layer = blockIdx.x - PTOT / 2;
        const float* src = layer == 0 ? w2l0 : w2l1;
        unsigned short* dh = layer == 0 ? bh0 : bh1;
        unsigned short* dl = layer == 0 ? bl0 : bl1;
        // 512 (kf,ct,lane) triples, 2 per thread, 8 elements each
#pragma unroll
        for (int i = 0; i < 2; ++i) {
            const int e = threadIdx.x * 2 + i;          // 0..511
            const int kf = e >> 8;
            const int ct = (e >> 6) & 3;
            const int ln = e & 63;
            const int kg = ln >> 4;
            const int rw = ln & 15;
#pragma unroll
            for (int j = 0; j < 8; ++j) {
                const float w = src[(kf * 32 + kg * 8 + j) * 64 + ct * 16 + rw];
                const unsigned short h = f2bf(w);
                dh[(size_t)e * 8 + j] = h;
                dl[(size_t)e * 8 + j] = f2bf(w - bf2f(h));
            }
        }
    }
}

// ---------------------------------------------------------------------------
// sa_fused_k<CB, LAST>: one 256-thread block (4 waves) per point.
// B fragments (W2 bf16 hi/lo) come PRE-SPLIT in fragment order -> 16 dwordx4.
// Wave w handles neighbor tiles t = w, w+4, ... of 16 neighbors each.
// Per tile: per-lane gather of h1 fragment from g (A row = lane&15, k-slice =
// (lane>>4)*8+j), split into bf16 hi/lo; 3 MFMAs per (kfrag,ct) ~ fp32 H1@W2;
// bias+lrelu+mask folded into running max. D layout (HW-confirmed r9):
// col = lane&15 (channel), row = (lane>>4)*4+reg (neighbor).
// One barrier; wave 0 runs the fused pointwise epilogue (+ next precompute).
// ---------------------------------------------------------------------------
template <int CB, bool LAST>
__global__ __launch_bounds__(256) void sa_fused_k(
    const float* __restrict__ g, const float* __restrict__ t,
    const unsigned short* __restrict__ idx, const int* __restrict__ cnt,
    const unsigned short* __restrict__ bhws, const unsigned short* __restrict__ blws,
    const float* __restrict__ b2,
    const float* __restrict__ wa, const float* __restrict__ ba,
    const float* __restrict__ wb, const float* __restrict__ bbias,
    const float* __restrict__ wc, const float* __restrict__ bc,
    const float* __restrict__ base, const float* __restrict__ pos,
    const float* __restrict__ w1n, const float* __restrict__ b1n,
    float* __restrict__ xout, float* __restrict__ gn, float* __restrict__ tn)
{
    const int p = blockIdx.x;
    const int lane = threadIdx.x & 63;
    const int wave = threadIdx.x >> 6;
    const int b = p >> 10;
    const int row = lane & 15;   // A-row / D-col position
    const int kg  = lane >> 4;   // k-group (8 consecutive k per group)

    // ---- B fragments: 16 vector loads from the pre-split arrays ----
    const short8* bhp = (const short8*)bhws;   // [(kf*4+ct)*64 + lane]
    const short8* blp = (const short8*)blws;
    short8 bh[2][4], bl[2][4];
#pragma unroll
    for (int kf = 0; kf < 2; ++kf)
#pragma unroll
        for (int ct = 0; ct < 4; ++ct) {
            bh[kf][ct] = bhp[(kf * 4 + ct) * 64 + lane];
            bl[kf][ct] = blp[(kf * 4 + ct) * 64 + lane];
        }

    float b2v[4];
#pragma unroll
    for (int ct = 0; ct < 4; ++ct) b2v[ct] = b2[ct * 16 + row];

    // t fragment: channels kg*8.. and 32+kg*8.. as float4 pairs
    const float* tp = t + (size_t)p * 64 + kg * 8;
    const float4 tva = *(const float4*)tp;
    const float4 tvb = *(const float4*)(tp + 4);
    const float4 tvc = *(const float4*)(tp + 32);
    const float4 tvd = *(const float4*)(tp + 36);
    const float tv0[8] = {tva.x, tva.y, tva.z, tva.w, tvb.x, tvb.y, tvb.z, tvb.w};
    const float tv1[8] = {tvc.x, tvc.y, tvc.z, tvc.w, tvd.x, tvd.y, tvd.z, tvd.w};

    const int craw = cnt[p];
    const int vc = craw < KK ? craw : KK;
    const unsigned short* mi = idx + (size_t)p * KK;
    const float* gbp = g + (size_t)b * NN * 64;

    float lmaxv[4] = {-FLT_MAX, -FLT_MAX, -FLT_MAX, -FLT_MAX};
    const int ntiles = (vc + 15) >> 4;

    for (int tile = wave; tile < ntiles; tile += 4) {
        const int j16 = tile * 16 + row;
        const int jc = j16 < vc ? j16 : vc - 1;          // clamp: masked later
        const int jidx = (int)mi[jc];
        const float* grow = gbp + (size_t)jidx * 64 + kg * 8;
        const float4 ga = *(const float4*)grow;
        const float4 gb2 = *(const float4*)(grow + 4);
        const float4 gc = *(const float4*)(grow + 32);
        const float4 gd = *(const float4*)(grow + 36);
        const float v0[8] = {ga.x, ga.y, ga.z, ga.w, gb2.x, gb2.y, gb2.z, gb2.w};
        const float v1[8] = {gc.x, gc.y, gc.z, gc.w, gd.x, gd.y, gd.z, gd.w};

        short8 ah0, al0, ah1, al1;
#pragma unroll
        for (int j = 0; j < 8; ++j) {
            const float h1a = lrelu(v0[j] - tv0[j]);
            const unsigned short ha = f2bf(h1a);
            ah0[j] = (short)ha;
            al0[j] = (short)f2bf(h1a - bf2f(ha));
            const float h1b = lrelu(v1[j] - tv1[j]);
            const unsigned short hb = f2bf(h1b);
            ah1[j] = (short)hb;
            al1[j] = (short)f2bf(h1b - bf2f(hb));
        }

#pragma unroll
        for (int ct = 0; ct < 4; ++ct) {
            f32x4 a = {0.0f, 0.0f, 0.0f, 0.0f};
            a = __builtin_amdgcn_mfma_f32_16x16x32_bf16(ah0, bh[0][ct], a, 0, 0, 0);
            a = __builtin_amdgcn_mfma_f32_16x16x32_bf16(al0, bh[0][ct], a, 0, 0, 0);
            a = __builtin_amdgcn_mfma_f32_16x16x32_bf16(ah0, bl[0][ct], a, 0, 0, 0);
            a = __builtin_amdgcn_mfma_f32_16x16x32_bf16(ah1, bh[1][ct], a, 0, 0, 0);
            a = __builtin_amdgcn_mfma_f32_16x16x32_bf16(al1, bh[1][ct], a, 0, 0, 0);
            a = __builtin_amdgcn_mfma_f32_16x16x32_bf16(ah1, bl[1][ct], a, 0, 0, 0);
#pragma unroll
            for (int r = 0; r < 4; ++r) {
                const int nb = tile * 16 + kg * 4 + r;   // D row = neighbor
                const float h2 = lrelu(a[r] + b2v[ct]);
                lmaxv[ct] = fmaxf(lmaxv[ct], nb < vc ? h2 : 0.0f);
            }
        }
    }

    // cross-lane (row-group) then cross-wave max
    __shared__ float red[4][64];
#pragma unroll
    for (int ct = 0; ct < 4; ++ct) {
        lmaxv[ct] = fmaxf(lmaxv[ct], __shfl_xor(lmaxv[ct], 16));
        lmaxv[ct] = fmaxf(lmaxv[ct], __shfl_xor(lmaxv[ct], 32));
    }
    if (lane < 16) {
#pragma unroll
        for (int ct = 0; ct < 4; ++ct) red[wave][ct * 16 + lane] = lmaxv[ct];
    }
    __syncthreads();

    if (wave == 0) {
        float m = fmaxf(fmaxf(red[0][lane], red[1][lane]),
                        fmaxf(red[2][lane], red[3][lane]));
        if (craw < KK) m = fmaxf(m, 0.0f);   // reference: zero slots in the max

        // pw: tmp = relu(m@wa + ba)
        float a0 = ba[lane], a1 = 0.0f, a2 = 0.0f, a3 = 0.0f;
#pragma unroll
        for (int o = 0; o < 64; o += 4) {
            a0 = fmaf(__shfl(m, o + 0), wa[(o + 0) * 64 + lane], a0);
            a1 = fmaf(__shfl(m, o + 1), wa[(o + 1) * 64 + lane], a1);
            a2 = fmaf(__shfl(m, o + 2), wa[(o + 2) * 64 + lane], a2);
            a3 = fmaf(__shfl(m, o + 3), wa[(o + 3) * 64 + lane], a3);
        }
        const float tmp = fmaxf((a0 + a1) + (a2 + a3), 0.0f);

        // xi = tmp@wb + bbias
        float e0 = bbias[lane], e1 = 0.0f, e2 = 0.0f, e3 = 0.0f;
#pragma unroll
        for (int o = 0; o < 64; o += 4) {
            e0 = fmaf(__shfl(tmp, o + 0), wb[(o + 0) * 64 + lane], e0);
            e1 = fmaf(__shfl(tmp, o + 1), wb[(o + 1) * 64 + lane], e1);
            e2 = fmaf(__shfl(tmp, o + 2), wb[(o + 2) * 64 + lane], e2);
            e3 = fmaf(__shfl(tmp, o + 3), wb[(o + 3) * 64 + lane], e3);
        }
        const float xi = (e0 + e1) + (e2 + e3);

        // residual: base@wc + bc
        float r0 = bc[lane], r1 = 0.0f, r2 = 0.0f, r3 = 0.0f;
        const float* bp = base + (size_t)p * CB;
#pragma unroll
        for (int f = 0; f < CB; f += 4) {
            r0 = fmaf(bp[f + 0], wc[(f + 0) * 64 + lane], r0);
            r1 = fmaf(bp[f + 1], wc[(f + 1) * 64 + lane], r1);
            r2 = fmaf(bp[f + 2], wc[(f + 2) * 64 + lane], r2);
            r3 = fmaf(bp[f + 3], wc[(f + 3) * 64 + lane], r3);
        }
        const float xv = ((r0 + r1) + (r2 + r3)) + xi;
        xout[(size_t)p * 64 + lane] = xv;

        if constexpr (!LAST) {
            const float px = pos[p * 3 + 0];
            const float py = pos[p * 3 + 1];
            const float pz = pos[p * 3 + 2];
            const float s = px * w1n[0 * 64 + lane] + py * w1n[1 * 64 + lane]
                          + pz * w1n[2 * 64 + lane];
            float g0 = b1n[lane] + s, g1v = 0.0f, g2 = 0.0f, g3 = 0.0f;
#pragma unroll
            for (int q = 0; q < 64; q += 4) {
                g0  = fmaf(__shfl(xv, q + 0), w1n[(3 + q + 0) * 64 + lane], g0);
                g1v = fmaf(__shfl(xv, q + 1), w1n[(3 + q + 1) * 64 + lane], g1v);
                g2  = fmaf(__shfl(xv, q + 2), w1n[(3 + q + 2) * 64 + lane], g2);
                g3  = fmaf(__shfl(xv, q + 3), w1n[(3 + q + 3) * 64 + lane], g3);
            }
            gn[(size_t)p * 64 + lane] = (g0 + g1v) + (g2 + g3);
            tn[(size_t)p * 64 + lane] = s;
        }
    }
}

// ---------------------------------------------------------------------------
extern "C" void kernel_launch(void* const* d_in, const int* in_sizes, int n_in,
                              void* d_out, int out_size, void* d_ws, size_t ws_size,
                              hipStream_t stream)
{
    const float* positions = (const float*)d_in[0];
    const float* features  = (const float*)d_in[1];
    const float* sa0_w1 = (const float*)d_in[2];
    const float* sa0_b1 = (const float*)d_in[3];
    const float* sa0_w2 = (const float*)d_in[4];
    const float* sa0_b2 = (const float*)d_in[5];
    const float* sa1_w1 = (const float*)d_in[6];
    const float* sa1_b1 = (const float*)d_in[7];
    const float* sa1_w2 = (const float*)d_in[8];
    const float* sa1_b2 = (const float*)d_in[9];
    const float* lin0_w1 = (const float*)d_in[10];
    const float* lin0_b1 = (const float*)d_in[11];
    const float* lin0_w2 = (const float*)d_in[12];
    const float* lin0_b2 = (const float*)d_in[13];
    const float* lin1_w1 = (const float*)d_in[14];
    const float* lin1_b1 = (const float*)d_in[15];
    const float* lin1_w2 = (const float*)d_in[16];
    const float* lin1_b2 = (const float*)d_in[17];
    const float* lt0_w = (const float*)d_in[18];
    const float* lt0_b = (const float*)d_in[19];
    const float* lt1_w = (const float*)d_in[20];
    const float* lt1_b = (const float*)d_in[21];

    const int P = PTOT;   // 2048 points

    // workspace layout (16B-aligned segments)
    unsigned short* idx = (unsigned short*)d_ws;               // P*K ushort (2 MiB)
    int* cnt = (int*)(idx + (size_t)P * KK);                   // P ints
    float* g0 = (float*)(cnt + P);                             // P*64 each:
    float* t0 = g0 + (size_t)P * OO;
    float* g1 = t0 + (size_t)P * OO;
    float* t1 = g1 + (size_t)P * OO;
    float* x  = t1 + (size_t)P * OO;
    unsigned short* bh0 = (unsigned short*)(x + (size_t)P * OO);  // 4096 shorts each
    unsigned short* bl0 = bh0 + 4096;
    unsigned short* bh1 = bl0 + 4096;
    unsigned short* bl1 = bh1 + 4096;

    float* out = (float*)d_out;

    // 1. ball query + layer-0 precompute + W2 pre-split (one dispatch)
    setup_k<<<P / 2 + 2, 256, 0, stream>>>(positions, features, sa0_w1, sa0_b1,
                                           sa0_w2, sa1_w2,
                                           idx, cnt, g0, t0, bh0, bl0, bh1, bl1);

    // 2. layer 0: SA-max + pointwise + lt residual + layer-1 precompute
    sa_fused_k<II, false><<<P, 256, 0, stream>>>(
        g0, t0, idx, cnt, bh0, bl0, sa0_b2,
        lin0_w1, lin0_b1, lin0_w2, lin0_b2, lt0_w, lt0_b,
        features, positions, sa1_w1, sa1_b1, x, g1, t1);

    // 3. layer 1: SA-max + pointwise + lt residual -> output
    sa_fused_k<OO, true><<<P, 256, 0, stream>>>(
        g1, t1, idx, cnt, bh1, bl1, sa1_b2,
        lin1_w1, lin1_b1, lin1_w2, lin1_b2, lt1_w, lt1_b,
        x, positions, nullptr, nullptr, out, nullptr, nullptr);
}

// Round 12
// 150.486 us; speedup vs baseline: 1.7980x; 1.0571x over previous
//
#include <hip/hip_runtime.h>
#include <cstdint>
#include <cfloat>

#define BB 2
#define NN 1024
#define KK 512
#define II 16
#define OO 64
#define R2 1.0f
#define PTOT (BB * NN)
#define PBLK (PTOT / 4)          // 512 blocks of 4 waves, one wave per point

typedef __attribute__((ext_vector_type(8))) short short8;   // 8 bf16 = 4 VGPR
typedef __attribute__((ext_vector_type(4))) float f32x4;

__device__ __forceinline__ float lrelu(float v) { return v > 0.0f ? v : 0.2f * v; }

__device__ __forceinline__ unsigned short f2bf(float f) {
    unsigned int x = __float_as_uint(f);
    return (unsigned short)((x + 0x7fffu + ((x >> 16) & 1u)) >> 16);
}
__device__ __forceinline__ float bf2f(unsigned short h) {
    return __uint_as_float(((unsigned int)h) << 16);
}

// ---------------------------------------------------------------------------
// setup_k: blocks [0, PBLK)  -> wave-per-point: ball query THEN layer-0
//                               precompute g0/t0 (no cross-wave coupling)
//          blocks PBLK,+1    -> W2 bf16 hi/lo pre-split in fragment order
// ---------------------------------------------------------------------------
__global__ __launch_bounds__(256) void setup_k(
    const float* __restrict__ pos, const float* __restrict__ feat,
    const float* __restrict__ w1, const float* __restrict__ b1,
    const float* __restrict__ w2l0, const float* __restrict__ w2l1,
    unsigned short* __restrict__ idx, int* __restrict__ cnt,
    float* __restrict__ g, float* __restrict__ t,
    unsigned short* __restrict__ bh0, unsigned short* __restrict__ bl0,
    unsigned short* __restrict__ bh1, unsigned short* __restrict__ bl1)
{
    const int wave = threadIdx.x >> 6;
    const int lane = threadIdx.x & 63;

    if (blockIdx.x < PBLK) {
        const int p = blockIdx.x * 4 + wave;
        const int b = p >> 10;
        // ---- ball query (ordered compaction) ----
        const float cx = pos[p * 3 + 0];
        const float cy = pos[p * 3 + 1];
        const float cz = pos[p * 3 + 2];
        const float* pb = pos + (size_t)b * NN * 3;
        unsigned short* op = idx + (size_t)p * KK;
        int count = 0;
        for (int jb = 0; jb < NN; jb += 64) {
            const int j = jb + lane;
            const float dx = pb[j * 3 + 0] - cx;
            const float dy = pb[j * 3 + 1] - cy;
            const float dz = pb[j * 3 + 2] - cz;
            const float d2 = dx * dx + dy * dy + dz * dz;
            const bool pred = d2 < R2;
            const unsigned long long m = __ballot(pred);
            const int before = __popcll(m & ((1ull << lane) - 1ull));
            const int w = count + before;
            if (pred && w < KK) op[w] = (unsigned short)j;
            count += __popcll(m);
        }
        if (lane == 0) cnt[p] = count;
        // ---- layer-0 precompute (C = II), lane = channel ----
        const int c = lane;
        const float s = cx * w1[0 * 64 + c] + cy * w1[1 * 64 + c] + cz * w1[2 * 64 + c];
        float acc = b1[c] + s;
        const float* f = feat + (size_t)p * II;
#pragma unroll
        for (int q = 0; q < II; ++q)
            acc = fmaf(f[q], w1[(3 + q) * 64 + c], acc);
        g[(size_t)p * 64 + c] = acc;
        t[(size_t)p * 64 + c] = s;
    } else {
        // ---- W2 fragment pre-split: one block per layer ----
        const int layer = blockIdx.x - PBLK;
        const float* src = layer == 0 ? w2l0 : w2l1;
        unsigned short* dh = layer == 0 ? bh0 : bh1;
        unsigned short* dl = layer == 0 ? bl0 : bl1;
#pragma unroll
        for (int i = 0; i < 2; ++i) {
            const int e = threadIdx.x * 2 + i;          // 0..511
            const int kf = e >> 8;
            const int ct = (e >> 6) & 3;
            const int ln = e & 63;
            const int kg = ln >> 4;
            const int rw = ln & 15;
#pragma unroll
            for (int j = 0; j < 8; ++j) {
                const float w = src[(kf * 32 + kg * 8 + j) * 64 + ct * 16 + rw];
                const unsigned short h = f2bf(w);
                dh[(size_t)e * 8 + j] = h;
                dl[(size_t)e * 8 + j] = f2bf(w - bf2f(h));
            }
        }
    }
}

// ---------------------------------------------------------------------------
// layer_k<CB, LAST>: WAVE-PER-POINT, no LDS, no barriers.
// Each wave: load pre-split W2 frags (16 dwordx4) -> sequential tile loop
// over its own point's neighbors (16/tile), 1-deep prefetched gathers,
// split-bf16 MFMA (HW-confirmed D layout: channel = ct*16+(lane&15),
// neighbor = tile*16+(lane>>4)*4+reg) -> cross-kg shfl max -> lane=channel
// rearrange -> full pointwise epilogue per wave (+ next-layer precompute).
// ---------------------------------------------------------------------------
template <int CB, bool LAST>
__global__ __launch_bounds__(256) void layer_k(
    const float* __restrict__ g, const float* __restrict__ t,
    const unsigned short* __restrict__ idx, const int* __restrict__ cnt,
    const unsigned short* __restrict__ bhws, const unsigned short* __restrict__ blws,
    const float* __restrict__ b2,
    const float* __restrict__ wa, const float* __restrict__ ba,
    const float* __restrict__ wb, const float* __restrict__ bbias,
    const float* __restrict__ wc, const float* __restrict__ bc,
    const float* __restrict__ base, const float* __restrict__ pos,
    const float* __restrict__ w1n, const float* __restrict__ b1n,
    float* __restrict__ xout, float* __restrict__ gn, float* __restrict__ tn)
{
    const int lane = threadIdx.x & 63;
    const int wave = threadIdx.x >> 6;
    const int p = blockIdx.x * 4 + wave;
    const int b = p >> 10;
    const int row = lane & 15;
    const int kg  = lane >> 4;

    // B fragments (pre-split, fragment order): 16 vector loads
    const short8* bhp = (const short8*)bhws;
    const short8* blp = (const short8*)blws;
    short8 bh[2][4], bl[2][4];
#pragma unroll
    for (int kf = 0; kf < 2; ++kf)
#pragma unroll
        for (int ct = 0; ct < 4; ++ct) {
            bh[kf][ct] = bhp[(kf * 4 + ct) * 64 + lane];
            bl[kf][ct] = blp[(kf * 4 + ct) * 64 + lane];
        }

    float b2v[4];
#pragma unroll
    for (int ct = 0; ct < 4; ++ct) b2v[ct] = b2[ct * 16 + row];

    const float* tp = t + (size_t)p * 64 + kg * 8;
    const float4 tva = *(const float4*)tp;
    const float4 tvb = *(const float4*)(tp + 4);
    const float4 tvc = *(const float4*)(tp + 32);
    const float4 tvd = *(const float4*)(tp + 36);
    const float tv0[8] = {tva.x, tva.y, tva.z, tva.w, tvb.x, tvb.y, tvb.z, tvb.w};
    const float tv1[8] = {tvc.x, tvc.y, tvc.z, tvc.w, tvd.x, tvd.y, tvd.z, tvd.w};

    const int craw = cnt[p];
    const int vc = craw < KK ? craw : KK;
    const unsigned short* mi = idx + (size_t)p * KK;
    const float* gbp = g + (size_t)b * NN * 64;

    float lmaxv[4] = {-FLT_MAX, -FLT_MAX, -FLT_MAX, -FLT_MAX};
    const int ntiles = (vc + 15) >> 4;

    // 1-deep prefetch pipeline over this wave's own tiles
    int jc = row < vc ? row : vc - 1;                   // tile 0, clamped
    const float* grow = gbp + (size_t)mi[jc] * 64 + kg * 8;
    float4 ca = *(const float4*)grow;
    float4 cb = *(const float4*)(grow + 4);
    float4 cc = *(const float4*)(grow + 32);
    float4 cd = *(const float4*)(grow + 36);

    for (int tile = 0; tile < ntiles; ++tile) {
        float4 na, nb4, nc, nd;
        if (tile + 1 < ntiles) {
            const int j16 = (tile + 1) * 16 + row;
            const int jn = j16 < vc ? j16 : vc - 1;
            const float* nrow = gbp + (size_t)mi[jn] * 64 + kg * 8;
            na = *(const float4*)nrow;
            nb4 = *(const float4*)(nrow + 4);
            nc = *(const float4*)(nrow + 32);
            nd = *(const float4*)(nrow + 36);
        }

        const float v0[8] = {ca.x, ca.y, ca.z, ca.w, cb.x, cb.y, cb.z, cb.w};
        const float v1[8] = {cc.x, cc.y, cc.z, cc.w, cd.x, cd.y, cd.z, cd.w};
        short8 ah0, al0, ah1, al1;
#pragma unroll
        for (int j = 0; j < 8; ++j) {
            const float h1a = lrelu(v0[j] - tv0[j]);
            const unsigned short ha = f2bf(h1a);
            ah0[j] = (short)ha;
            al0[j] = (short)f2bf(h1a - bf2f(ha));
            const float h1b = lrelu(v1[j] - tv1[j]);
            const unsigned short hb = f2bf(h1b);
            ah1[j] = (short)hb;
            al1[j] = (short)f2bf(h1b - bf2f(hb));
        }

#pragma unroll
        for (int ct = 0; ct < 4; ++ct) {
            f32x4 a = {0.0f, 0.0f, 0.0f, 0.0f};
            a = __builtin_amdgcn_mfma_f32_16x16x32_bf16(ah0, bh[0][ct], a, 0, 0, 0);
            a = __builtin_amdgcn_mfma_f32_16x16x32_bf16(al0, bh[0][ct], a, 0, 0, 0);
            a = __builtin_amdgcn_mfma_f32_16x16x32_bf16(ah0, bl[0][ct], a, 0, 0, 0);
            a = __builtin_amdgcn_mfma_f32_16x16x32_bf16(ah1, bh[1][ct], a, 0, 0, 0);
            a = __builtin_amdgcn_mfma_f32_16x16x32_bf16(al1, bh[1][ct], a, 0, 0, 0);
            a = __builtin_amdgcn_mfma_f32_16x16x32_bf16(ah1, bl[1][ct], a, 0, 0, 0);
#pragma unroll
            for (int r = 0; r < 4; ++r) {
                const int nb = tile * 16 + kg * 4 + r;   // D row = neighbor
                const float h2 = lrelu(a[r] + b2v[ct]);
                lmaxv[ct] = fmaxf(lmaxv[ct], nb < vc ? h2 : 0.0f);
            }
        }
        ca = na; cb = nb4; cc = nc; cd = nd;
    }

    // cross-kg max (all lanes with equal lane&15 converge)
#pragma unroll
    for (int ct = 0; ct < 4; ++ct) {
        lmaxv[ct] = fmaxf(lmaxv[ct], __shfl_xor(lmaxv[ct], 16));
        lmaxv[ct] = fmaxf(lmaxv[ct], __shfl_xor(lmaxv[ct], 32));
    }
    // rearrange to lane = channel: channel c -> lmaxv[c>>4] of lane c&15
    const float s0 = __shfl(lmaxv[0], row);
    const float s1 = __shfl(lmaxv[1], row);
    const float s2 = __shfl(lmaxv[2], row);
    const float s3 = __shfl(lmaxv[3], row);
    float m = lane < 16 ? s0 : lane < 32 ? s1 : lane < 48 ? s2 : s3;
    if (craw < KK) m = fmaxf(m, 0.0f);   // reference: zero slots in the max

    // ---- per-wave pointwise epilogue ----
    float a0 = ba[lane], a1 = 0.0f, a2 = 0.0f, a3 = 0.0f;
#pragma unroll
    for (int o = 0; o < 64; o += 4) {
        a0 = fmaf(__shfl(m, o + 0), wa[(o + 0) * 64 + lane], a0);
        a1 = fmaf(__shfl(m, o + 1), wa[(o + 1) * 64 + lane], a1);
        a2 = fmaf(__shfl(m, o + 2), wa[(o + 2) * 64 + lane], a2);
        a3 = fmaf(__shfl(m, o + 3), wa[(o + 3) * 64 + lane], a3);
    }
    const float tmp = fmaxf((a0 + a1) + (a2 + a3), 0.0f);

    float e0 = bbias[lane], e1 = 0.0f, e2 = 0.0f, e3 = 0.0f;
#pragma unroll
    for (int o = 0; o < 64; o += 4) {
        e0 = fmaf(__shfl(tmp, o + 0), wb[(o + 0) * 64 + lane], e0);
        e1 = fmaf(__shfl(tmp, o + 1), wb[(o + 1) * 64 + lane], e1);
        e2 = fmaf(__shfl(tmp, o + 2), wb[(o + 2) * 64 + lane], e2);
        e3 = fmaf(__shfl(tmp, o + 3), wb[(o + 3) * 64 + lane], e3);
    }
    const float xi = (e0 + e1) + (e2 + e3);

    float r0 = bc[lane], r1 = 0.0f, r2 = 0.0f, r3 = 0.0f;
    const float* bp = base + (size_t)p * CB;
#pragma unroll
    for (int f = 0; f < CB; f += 4) {
        r0 = fmaf(bp[f + 0], wc[(f + 0) * 64 + lane], r0);
        r1 = fmaf(bp[f + 1], wc[(f + 1) * 64 + lane], r1);
        r2 = fmaf(bp[f + 2], wc[(f + 2) * 64 + lane], r2);
        r3 = fmaf(bp[f + 3], wc[(f + 3) * 64 + lane], r3);
    }
    const float xv = ((r0 + r1) + (r2 + r3)) + xi;
    xout[(size_t)p * 64 + lane] = xv;

    if constexpr (!LAST) {
        const float px = pos[p * 3 + 0];
        const float py = pos[p * 3 + 1];
        const float pz = pos[p * 3 + 2];
        const float s = px * w1n[0 * 64 + lane] + py * w1n[1 * 64 + lane]
                      + pz * w1n[2 * 64 + lane];
        float g0 = b1n[lane] + s, g1v = 0.0f, g2 = 0.0f, g3 = 0.0f;
#pragma unroll
        for (int q = 0; q < 64; q += 4) {
            g0  = fmaf(__shfl(xv, q + 0), w1n[(3 + q + 0) * 64 + lane], g0);
            g1v = fmaf(__shfl(xv, q + 1), w1n[(3 + q + 1) * 64 + lane], g1v);
            g2  = fmaf(__shfl(xv, q + 2), w1n[(3 + q + 2) * 64 + lane], g2);
            g3  = fmaf(__shfl(xv, q + 3), w1n[(3 + q + 3) * 64 + lane], g3);
        }
        gn[(size_t)p * 64 + lane] = (g0 + g1v) + (g2 + g3);
        tn[(size_t)p * 64 + lane] = s;
    }
}

// ---------------------------------------------------------------------------
extern "C" void kernel_launch(void* const* d_in, const int* in_sizes, int n_in,
                              void* d_out, int out_size, void* d_ws, size_t ws_size,
                              hipStream_t stream)
{
    const float* positions = (const float*)d_in[0];
    const float* features  = (const float*)d_in[1];
    const float* sa0_w1 = (const float*)d_in[2];
    const float* sa0_b1 = (const float*)d_in[3];
    const float* sa0_w2 = (const float*)d_in[4];
    const float* sa0_b2 = (const float*)d_in[5];
    const float* sa1_w1 = (const float*)d_in[6];
    const float* sa1_b1 = (const float*)d_in[7];
    const float* sa1_w2 = (const float*)d_in[8];
    const float* sa1_b2 = (const float*)d_in[9];
    const float* lin0_w1 = (const float*)d_in[10];
    const float* lin0_b1 = (const float*)d_in[11];
    const float* lin0_w2 = (const float*)d_in[12];
    const float* lin0_b2 = (const float*)d_in[13];
    const float* lin1_w1 = (const float*)d_in[14];
    const float* lin1_b1 = (const float*)d_in[15];
    const float* lin1_w2 = (const float*)d_in[16];
    const float* lin1_b2 = (const float*)d_in[17];
    const float* lt0_w = (const float*)d_in[18];
    const float* lt0_b = (const float*)d_in[19];
    const float* lt1_w = (const float*)d_in[20];
    const float* lt1_b = (const float*)d_in[21];

    const int P = PTOT;   // 2048 points

    unsigned short* idx = (unsigned short*)d_ws;               // P*K ushort (2 MiB)
    int* cnt = (int*)(idx + (size_t)P * KK);                   // P ints
    float* g0 = (float*)(cnt + P);                             // P*64 each:
    float* t0 = g0 + (size_t)P * OO;
    float* g1 = t0 + (size_t)P * OO;
    float* t1 = g1 + (size_t)P * OO;
    float* x  = t1 + (size_t)P * OO;
    unsigned short* bh0 = (unsigned short*)(x + (size_t)P * OO);  // 4096 shorts each
    unsigned short* bl0 = bh0 + 4096;
    unsigned short* bh1 = bl0 + 4096;
    unsigned short* bl1 = bh1 + 4096;

    float* out = (float*)d_out;

    setup_k<<<PBLK + 2, 256, 0, stream>>>(positions, features, sa0_w1, sa0_b1,
                                          sa0_w2, sa1_w2,
                                          idx, cnt, g0, t0, bh0, bl0, bh1, bl1);

    layer_k<II, false><<<PBLK, 256, 0, stream>>>(
        g0, t0, idx, cnt, bh0, bl0, sa0_b2,
        lin0_w1, lin0_b1, lin0_w2, lin0_b2, lt0_w, lt0_b,
        features, positions, sa1_w1, sa1_b1, x, g1, t1);

    layer_k<OO, true><<<PBLK, 256, 0, stream>>>(
        g1, t1, idx, cnt, bh1, bl1, sa1_b2,
        lin1_w1, lin1_b1, lin1_w2, lin1_b2, lt1_w, lt1_b,
        x, positions, nullptr, nullptr, out, nullptr, nullptr);
}